// Round 8
// baseline (232.325 us; speedup 1.0000x reference)
//
#include <hip/hip_runtime.h>
#include <hip/hip_bf16.h>
#include <cstdint>
#include <cstddef>

#define BB 2
#define NN 2048
#define DD 1024
#define HH 16
#define DKK 64
#define SCALE 0.125f
#define LOG2E 1.4426950408889634f

typedef __bf16 bf16;
typedef __bf16 bf16x4 __attribute__((ext_vector_type(4)));
typedef __bf16 bf16x8 __attribute__((ext_vector_type(8)));
typedef float f32x4 __attribute__((ext_vector_type(4)));
typedef float f32x16 __attribute__((ext_vector_type(16)));
typedef short s16x4 __attribute__((ext_vector_type(4)));

// async global->LDS, 16B/lane; LDS dst = wave-uniform base + lane*16.
#define GLD(gp, lp)                                                            \
  __builtin_amdgcn_global_load_lds(                                            \
      (const __attribute__((address_space(1))) void*)(gp),                     \
      (__attribute__((address_space(3))) void*)(lp), 16, 0, 0)

// ---------------- fp32 -> bf16 convert, all 7 tensors in one dispatch ------
struct CvtArgs { const float* s[7]; bf16* d[7]; int n[7]; };

__global__ void k_cvt(CvtArgs a) {
  const int seg = blockIdx.y;
  const float* __restrict__ s = a.s[seg];
  bf16* __restrict__ d = a.d[seg];
  int i = (blockIdx.x * 256 + threadIdx.x) * 8;
  if (i >= a.n[seg]) return;
  float4 f0 = *(const float4*)(s + i);
  float4 f1 = *(const float4*)(s + i + 4);
  bf16x8 o;
  o[0] = (bf16)f0.x; o[1] = (bf16)f0.y; o[2] = (bf16)f0.z; o[3] = (bf16)f0.w;
  o[4] = (bf16)f1.x; o[5] = (bf16)f1.y; o[6] = (bf16)f1.z; o[7] = (bf16)f1.w;
  *(bf16x8*)(d + i) = o;
}

// ---------------- QKV GEMM: out = oscale*(A @ W^T + bias) ------------------
// 128x128 tile, BK=64, GLD staging, 2-barrier. (unchanged from round 7)
__device__ __forceinline__ void gemm_body(
    const bf16* __restrict__ A, const bf16* __restrict__ W,
    const float* __restrict__ bias, bf16* __restrict__ outB, int mode,
    float oscale, int m0, int n0) {
  const int K = 1024;
  __shared__ bf16 lA[128 * 64];
  __shared__ bf16 lB[128 * 64];
  const int t = threadIdx.x;
  const int lane = t & 63, quad = lane >> 4, l16 = lane & 15, w = t >> 6;
  const int wm = (w >> 1) * 64, wn = (w & 1) * 64;

  f32x4 acc[4][4] = {};

  const bf16* gA[4]; const bf16* gB[4];
#pragma unroll
  for (int i4 = 0; i4 < 4; i4++) {
    int i = i4 * 256 + t;
    int r = i >> 3, c = (i & 7) ^ (r & 7);
    gA[i4] = A + (size_t)(m0 + r) * K + c * 8;
    gB[i4] = W + (size_t)(n0 + r) * K + c * 8;
  }

  for (int kb = 0; kb < K; kb += 64) {
    __syncthreads();
#pragma unroll
    for (int i4 = 0; i4 < 4; i4++) GLD(gA[i4] + kb, lA + (i4 * 256 + t) * 8);
#pragma unroll
    for (int i4 = 0; i4 < 4; i4++) GLD(gB[i4] + kb, lB + (i4 * 256 + t) * 8);
    __syncthreads();

#pragma unroll
    for (int kb2 = 0; kb2 < 2; kb2++) {
      bf16x8 af[4], bfr[4];
      const int ch = ((kb2 * 4 + quad) ^ (l16 & 7)) * 8;
#pragma unroll
      for (int i = 0; i < 4; i++) {
        af[i] = *(const bf16x8*)(lA + (wm + i * 16 + l16) * 64 + ch);
        bfr[i] = *(const bf16x8*)(lB + (wn + i * 16 + l16) * 64 + ch);
      }
#pragma unroll
      for (int mi = 0; mi < 4; mi++)
#pragma unroll
        for (int ni = 0; ni < 4; ni++)
          acc[mi][ni] = __builtin_amdgcn_mfma_f32_16x16x32_bf16(
              af[mi], bfr[ni], acc[mi][ni], 0, 0, 0);
    }
  }

#pragma unroll
  for (int mi = 0; mi < 4; mi++) {
#pragma unroll
    for (int ni = 0; ni < 4; ni++) {
#pragma unroll
      for (int r = 0; r < 4; r++) {
        int gm = m0 + wm + mi * 16 + quad * 4 + r;
        int gn = n0 + wn + ni * 16 + l16;
        float v = (acc[mi][ni][r] + bias[gn]) * oscale;
        int b = gm >> 11, row = gm & 2047;
        int h = gn >> 6, dk = gn & 63;
        if (mode == 2)
          outB[((size_t)(b * HH + h) * DKK + dk) * NN + row] = (bf16)v;
        else
          outB[((size_t)(b * HH + h) * NN + row) * DKK + dk] = (bf16)v;
      }
    }
  }
}

struct QkvArgs {
  const bf16* A; const bf16* W; const float* b[3]; bf16* o[3]; float sc0;
};

// grid (x=m-panel 32, y=n-panel 8, z=gemm): XCD = m-panel%8 -> A fetched ~1x.
__global__ __launch_bounds__(256, 3) void k_qkv(QkvArgs g) {
  const int z = blockIdx.z;
  gemm_body(g.A + (size_t)z * 4194304, g.W + (size_t)z * 1048576, g.b[z],
            g.o[z], z == 2 ? 2 : 0, z == 0 ? g.sc0 : 1.0f, blockIdx.x * 128,
            blockIdx.y * 128);
}

// ---------------- O-projection: BK=128, 128x64 tile, 48KB LDS --------------
// 32 MFMA per 2-barrier K-step (vs 16 at BK=64): halves exposed drains.
// grid (x=m-panel 32, y=n-panel 16), 3 blocks/CU.
__global__ __launch_bounds__(256, 3) void k_oproj(
    const bf16* __restrict__ A, const bf16* __restrict__ W,
    const float* __restrict__ bias, float* __restrict__ out) {
  const int K = 1024;
  __shared__ bf16 lA[128 * 128];  // 32KB
  __shared__ bf16 lB[64 * 128];   // 16KB
  const int t = threadIdx.x;
  const int lane = t & 63, quad = lane >> 4, l16 = lane & 15, w = t >> 6;
  const int wm = (w >> 1) * 64, wn = (w & 1) * 32;
  const int m0 = blockIdx.x * 128, n0 = blockIdx.y * 64;

  f32x4 acc[4][2] = {};

  // staging: 16 chunks(16B)/row, slot c holds global chunk c^(row&15)
  const bf16* gA[8]; const bf16* gB[4];
#pragma unroll
  for (int i8 = 0; i8 < 8; i8++) {
    int i = i8 * 256 + t;
    int r = i >> 4, c = (i & 15) ^ (r & 15);
    gA[i8] = A + (size_t)(m0 + r) * K + c * 8;
  }
#pragma unroll
  for (int i4 = 0; i4 < 4; i4++) {
    int i = i4 * 256 + t;
    int r = i >> 4, c = (i & 15) ^ (r & 15);
    gB[i4] = W + (size_t)(n0 + r) * K + c * 8;
  }

  for (int kb = 0; kb < K; kb += 128) {
    __syncthreads();
#pragma unroll
    for (int i8 = 0; i8 < 8; i8++) GLD(gA[i8] + kb, lA + (i8 * 256 + t) * 8);
#pragma unroll
    for (int i4 = 0; i4 < 4; i4++) GLD(gB[i4] + kb, lB + (i4 * 256 + t) * 8);
    __syncthreads();

#pragma unroll
    for (int kb2 = 0; kb2 < 4; kb2++) {
      bf16x8 af[4], bfr[2];
      const int ch = ((kb2 * 4 + quad) ^ (l16 & 15)) * 8;
#pragma unroll
      for (int i = 0; i < 4; i++)
        af[i] = *(const bf16x8*)(lA + (wm + i * 16 + l16) * 128 + ch);
#pragma unroll
      for (int i = 0; i < 2; i++)
        bfr[i] = *(const bf16x8*)(lB + (wn + i * 16 + l16) * 128 + ch);
#pragma unroll
      for (int mi = 0; mi < 4; mi++)
#pragma unroll
        for (int ni = 0; ni < 2; ni++)
          acc[mi][ni] = __builtin_amdgcn_mfma_f32_16x16x32_bf16(
              af[mi], bfr[ni], acc[mi][ni], 0, 0, 0);
    }
  }

#pragma unroll
  for (int mi = 0; mi < 4; mi++)
#pragma unroll
    for (int ni = 0; ni < 2; ni++)
#pragma unroll
      for (int r = 0; r < 4; r++) {
        int gm = m0 + wm + mi * 16 + quad * 4 + r;
        int gn = n0 + wn + ni * 16 + l16;
        out[(size_t)gm * 1024 + gn] = acc[mi][ni][r] + bias[gn];
      }
}

// ---------------- flash attention: 32x32 MFMA geometry ---------------------
// Qp pre-scaled by SCALE*LOG2E. Qp,Kp:[B][H][N][DK]; Vt:[B][H][DK][N];
// Ao:[B][N][H*DK]. 512 thr = 4 qrow-groups (wq, 32 rows) x 2 key-halves (kh).
// S^T = K Q^T via mfma_f32_32x32x16_bf16 (C: col=qrow=lane&31,
// row=key=(reg&3)+8*(reg>>2)+4*(lane>>5)) -- these rows are EXACTLY the
// B-operand k-pattern of mfma_f32_32x32x8bf16_1k (k=(lane>>5)*4+j per 8-key
// block = C regs 4b..4b+3), so P feeds PV from registers at 16k FLOP/inst.
__global__ __launch_bounds__(512, 4) void k_attn(
    const bf16* __restrict__ Qp, const bf16* __restrict__ Kp,
    const bf16* __restrict__ Vt, bf16* __restrict__ Ao) {
  __shared__ bf16 lK[2][128 * 64];  // 2 x 16KB
  __shared__ bf16 lV[2][64 * 128];  // 2 x 16KB
  const int t = threadIdx.x;
  const int lane = t & 63, l32 = lane & 31, hi = lane >> 5, w = t >> 6;
  const int wq = w & 3;   // qrow group (32 rows)
  const int kh = w >> 2;  // key half (64 keys)
  const int bh = blockIdx.x;  // XCD = bh%8 -> K/V L2-resident per XCD
  const int qt = blockIdx.y;
  const bf16* Qb = Qp + (size_t)bh * NN * DKK;
  const bf16* Kb = Kp + (size_t)bh * NN * DKK;
  const bf16* Vb = Vt + (size_t)bh * DKK * NN;

  // Q B-frags (32x32x16: n=qrow=l32, k=hi*8+j within 16-k block)
  const int qr = qt * 128 + wq * 32 + l32;
  bf16x8 qf[4];
#pragma unroll
  for (int kblk = 0; kblk < 4; kblk++)
    qf[kblk] = *(const bf16x8*)(Qb + (size_t)qr * DKK + kblk * 16 + hi * 8);

  float lj = 0.f;
  f32x16 oaccT[2] = {};  // O^T: rows dk = nt*32+(reg&3)+8*(reg>>2)+4*hi

  // staging: lK chunk i: row i>>3, gchunk (i&7)^(r&7); lV: row i>>4, (i&15)^(r&15)
  const bf16* gK[2]; const bf16* gV[2];
#pragma unroll
  for (int i2 = 0; i2 < 2; i2++) {
    int i = i2 * 512 + t;
    int rK = i >> 3, cK = (i & 7) ^ (rK & 7);
    gK[i2] = Kb + (size_t)rK * DKK + cK * 8;
    int rV = i >> 4, cV = (i & 15) ^ (rV & 15);
    gV[i2] = Vb + (size_t)rV * NN + cV * 8;
  }

  // prologue: stage tile 0 into buffer 0
#pragma unroll
  for (int i2 = 0; i2 < 2; i2++) {
    GLD(gK[i2], &lK[0][(i2 * 512 + t) * 8]);
    GLD(gV[i2], &lV[0][(i2 * 512 + t) * 8]);
  }

  int p = 0;
  for (int kt = 0; kt < NN; kt += 128) {
    __syncthreads();
    if (kt + 128 < NN) {
#pragma unroll
      for (int i2 = 0; i2 < 2; i2++) {
        GLD(gK[i2] + (size_t)(kt + 128) * DKK, &lK[p ^ 1][(i2 * 512 + t) * 8]);
        GLD(gV[i2] + (kt + 128), &lV[p ^ 1][(i2 * 512 + t) * 8]);
      }
    }

    // S^T = K Q^T over this wave's key half: 2 subtiles of 32 keys
    f32x16 s[2];
#pragma unroll
    for (int kk = 0; kk < 2; kk++) {
      const int keyrow = kh * 64 + kk * 32 + l32;
      const bf16* kbase = &lK[p][keyrow * 64];
      f32x16 z = {};
#pragma unroll
      for (int kblk = 0; kblk < 4; kblk++) {
        const int cc = kblk * 2 + hi;
        bf16x8 kf = *(const bf16x8*)(kbase + ((cc ^ (keyrow & 7)) * 8));
        z = __builtin_amdgcn_mfma_f32_32x32x16_bf16(kf, qf[kblk], z, 0, 0, 0);
      }
      s[kk] = z;
    }

    // P = exp2(S); C regs 4b..4b+3 ARE the PV B-frag for key-block b
    s16x4 pa[2][4];
    float rs = 0.f;
#pragma unroll
    for (int kk = 0; kk < 2; kk++)
#pragma unroll
      for (int b = 0; b < 4; b++) {
        bf16x4 pb;
#pragma unroll
        for (int j = 0; j < 4; j++) {
          float pe = __builtin_amdgcn_exp2f(s[kk][4 * b + j]);
          rs += pe;
          pb[j] = (bf16)pe;
        }
        pa[kk][b] = __builtin_bit_cast(s16x4, pb);
      }
    lj += rs;

    // O^T += V^T P : A = V-frag (32x32x8: m=dk=l32, k=hi*4+j), B = P (regs)
#pragma unroll
    for (int nt = 0; nt < 2; nt++) {
      const int rv = nt * 32 + l32;
      const bf16* rowbase = &lV[p][rv * 128];
#pragma unroll
      for (int kk = 0; kk < 2; kk++)
#pragma unroll
        for (int b = 0; b < 4; b++) {
          const int cc = kh * 8 + kk * 4 + b;
          s16x4 vb = __builtin_bit_cast(
              s16x4,
              *(const bf16x4*)(rowbase + ((cc ^ (rv & 15)) * 8) + hi * 4));
          oaccT[nt] = __builtin_amdgcn_mfma_f32_32x32x8bf16_1k(
              vb, pa[kk][b], oaccT[nt], 0, 0, 0);
        }
    }
    p ^= 1;
  }

  // lane and lane+32 hold complementary keys for the same qrow
  lj += __shfl_xor(lj, 32);

  // ---- cross key-half reduction via LDS (once) ----
  __syncthreads();
  float* redO = (float*)&lK[0][0];  // 256 lanes x 32 f32 = 32KB
  float* redL = (float*)&lV[0][0];
  if (kh == 1) {
    float* dst = redO + (wq * 64 + lane) * 32;
    *(f32x16*)(dst) = oaccT[0];
    *(f32x16*)(dst + 16) = oaccT[1];
    redL[wq * 64 + lane] = lj;
  }
  __syncthreads();
  if (kh == 0) {
    const float* src = redO + (wq * 64 + lane) * 32;
    oaccT[0] += *(const f32x16*)(src);
    oaccT[1] += *(const f32x16*)(src + 16);
    lj += redL[wq * 64 + lane];

    const float inv = 1.0f / lj;
    const int b = bh >> 4, h = bh & 15;
    bf16* dst = Ao + ((size_t)(b * NN) + qr) * DD + h * DKK + hi * 4;
#pragma unroll
    for (int nt = 0; nt < 2; nt++)
#pragma unroll
      for (int g = 0; g < 4; g++) {
        bf16x4 ov;
#pragma unroll
        for (int j = 0; j < 4; j++) ov[j] = (bf16)(oaccT[nt][4 * g + j] * inv);
        *(bf16x4*)(dst + nt * 32 + g * 8) = ov;
      }
  }
}

extern "C" void kernel_launch(void* const* d_in, const int* in_sizes, int n_in,
                              void* d_out, int out_size, void* d_ws,
                              size_t ws_size, hipStream_t stream) {
  const float* qin = (const float*)d_in[0];
  const float* kin = (const float*)d_in[1];
  const float* vin = (const float*)d_in[2];
  const float* Wq = (const float*)d_in[3];
  const float* bq = (const float*)d_in[4];
  const float* Wk = (const float*)d_in[5];
  const float* bk = (const float*)d_in[6];
  const float* Wv = (const float*)d_in[7];
  const float* bv = (const float*)d_in[8];
  const float* Wo = (const float*)d_in[9];
  const float* bo = (const float*)d_in[10];
  float* out = (float*)d_out;

  const int MN = BB * NN * DD;  // 4M elems
  const int WNel = DD * DD;     // 1M elems
  bf16* ws = (bf16*)d_ws;
  bf16* Xb = ws;                 // 12M elems (q,k,v bf16)
  bf16* Wb = Xb + 3 * MN;        // 4M elems (Wq,Wk,Wv,Wo bf16)
  bf16* Qp = Wb + 4 * WNel;      // 4M
  bf16* Kp = Qp + MN;            // 4M
  bf16* Vt = Kp + MN;            // 4M   -> 28M elems = 56MB
  bf16* Ao = Xb;                 // alias: Xb dead after k_qkv

  CvtArgs ca{{qin, kin, vin, Wq, Wk, Wv, Wo},
             {Xb, Xb + MN, Xb + 2 * MN, Wb, Wb + WNel, Wb + 2 * WNel,
              Wb + 3 * WNel},
             {MN, MN, MN, WNel, WNel, WNel, WNel}};
  k_cvt<<<dim3(2048, 7), 256, 0, stream>>>(ca);

  QkvArgs g{Xb, Wb, {bq, bk, bv}, {Qp, Kp, Vt}, SCALE * LOG2E};
  k_qkv<<<dim3(32, 8, 3), 256, 0, stream>>>(g);
  k_attn<<<dim3(32, 16), 512, 0, stream>>>(Qp, Kp, Vt, Ao);
  k_oproj<<<dim3(32, 16), 256, 0, stream>>>(Ao, Wb + 3 * WNel, bo, out);
}